// Round 3
// baseline (70.846 us; speedup 1.0000x reference)
//
#include <hip/hip_runtime.h>
#include <hip/hip_fp16.h>
#include <math.h>

#define TT 8192
#define FF 64
#define TILE 32
#define NW 8

__device__ __forceinline__ float rcpf(float x) { return __builtin_amdgcn_rcpf(x); }

// ---- prep: softmax rows of W; pack {softmax_w[i][j], proj_w[i][j]} as half2 at wp[j*64+i] ----
__global__ void prep_kernel(const float* __restrict__ W,
                            const float* __restrict__ PW,
                            __half2* __restrict__ wp) {
    const int lane = threadIdx.x;   // j
    const int wv   = threadIdx.y;   // 0..3
    for (int it = 0; it < 16; ++it) {
        const int r = wv * 16 + it; // i
        float v = W[r * 64 + lane];
        float m = v;
        #pragma unroll
        for (int off = 32; off >= 1; off >>= 1)
            m = fmaxf(m, __shfl_xor(m, off, 64));
        float e = __expf(v - m);
        float s = e;
        #pragma unroll
        for (int off = 32; off >= 1; off >>= 1)
            s += __shfl_xor(s, off, 64);
        const float w = e * rcpf(s);
        const float p = PW[r * 64 + lane];
        wp[lane * 64 + r] = __floats2half2_rn(w, p);   // wp[j][i]
    }
}

// ---- fused main kernel: 512 threads = 8 waves, 32 rows/block, 4 rows/wave ----
__global__ __launch_bounds__(512, 8)
void mcao_main(const float* __restrict__ x,
               const __half2* __restrict__ wp,
               const float* __restrict__ pb,
               const float* __restrict__ kap,
               const float* __restrict__ coeffs,
               float* __restrict__ out,
               float* __restrict__ memout) {
    __shared__ float   xs[TILE * 64];       //  8192 B
    __shared__ __half2 wp_lds[64 * 64];     // 16384 B
    __shared__ float2  tu[NW][4][64];       // 16384 B   (total 40960 -> 4 blocks/CU = 32 waves)

    const int tid  = threadIdx.x;
    const int lane = tid & 63;
    const int wv   = tid >> 6;              // 0..7

    // XCD-aware bijective swizzle: 1024 blocks -> 128 consecutive tiles per XCD
    const int sw = (blockIdx.x & 7) * 128 + (blockIdx.x >> 3);
    const int b  = sw >> 8;                 // 0..3
    const int t0 = (sw & 255) * TILE;
    const float* xb = x + (size_t)b * TT * FF;

    // stage xs (32 rows = 512 float4, one per thread) and wp (1024 float4, 2 per thread)
    reinterpret_cast<float4*>(xs)[tid] =
        reinterpret_cast<const float4*>(xb + t0 * 64)[tid];
    #pragma unroll
    for (int k = 0; k < 2; ++k)
        reinterpret_cast<float4*>(wp_lds)[tid + 512 * k] =
            reinterpret_cast<const float4*>(wp)[tid + 512 * k];

    // ---- FIR from global (L2-hot via XCD swizzle): wave owns rows 4wv..4wv+3 ----
    float macc[4] = {0.f, 0.f, 0.f, 0.f};
    {
        const int tbase = t0 + 4 * wv - 50;   // stream row for s=0
        #pragma unroll
        for (int sc = 0; sc < 7; ++sc) {      // 7 chunks of 8 = 56 >= 54 needed
            float xv[8];
            #pragma unroll
            for (int q = 0; q < 8; ++q) {
                const int s = sc * 8 + q;
                const int t = tbase + s;
                xv[q] = (s < 54 && t >= 0) ? xb[t * 64 + lane] : 0.f;
            }
            #pragma unroll
            for (int q = 0; q < 8; ++q) {
                const int s = sc * 8 + q;
                #pragma unroll
                for (int r = 0; r < 4; ++r) {
                    const int k = 50 + r - s;
                    if (0 <= k && k <= 50)
                        macc[r] = fmaf(coeffs[k], xv[q], macc[r]);
                }
            }
        }
    }

    __syncthreads();

    const float kappa  = kap[0];
    const float inv1mr = rcpf(1.f - __expf(-kappa));
    const float pbias  = pb[lane];

    // per-row feature values for this wave's 4 rows
    float ti[4], ui[4];
    #pragma unroll
    for (int r = 0; r < 4; ++r) {
        const float xi = xs[(4 * wv + r) * 64 + lane];
        const float E  = __expf(2.f * xi);
        ti[r] = fmaf(-2.f, rcpf(E + 1.f), 1.f);   // tanh(xi)
        ui[r] = __expf(-fabsf(xi));               // e^{-|xi|}
        tu[wv][r][lane] = make_float2(ti[r], ui[r]);
    }
    // tu is wave-private: in-wave LDS ordering, no barrier needed

    float cacc[4] = {0.f, 0.f, 0.f, 0.f};
    float pacc[4] = {0.f, 0.f, 0.f, 0.f};
    #pragma unroll 8
    for (int j = 0; j < 64; ++j) {
        const __half2 wpj = wp_lds[j * 64 + lane];   // 2-way (free) bank pattern
        const float wj = __low2float(wpj);
        const float pj = __high2float(wpj);
        #pragma unroll
        for (int r = 0; r < 4; ++r) {
            const float2 tj = tu[wv][r][j];              // b64 broadcast
            const float  xj = xs[(4 * wv + r) * 64 + j]; // b32 broadcast
            const float d1  = fmaf(-ti[r], tj.x, 1.f);   // 1 - ti*tj
            const float d2  = fmaf(ui[r], tj.y, 1.f);    // 1 + ui*uj
            const float rrp = rcpf(d1 * d2);
            const float num = ti[r] - tj.x;
            cacc[r] = fmaf(num * wj, rrp, cacc[r]);
            pacc[r] = fmaf(xj, pj, pacc[r]);
        }
    }

    #pragma unroll
    for (int r = 0; r < 4; ++r) {
        const int   t    = t0 + 4 * wv + r;
        const float ksum = (1.f - __expf(-kappa * (float)(t + 1))) * inv1mr;
        const float m    = macc[r];
        const size_t o   = (size_t)(b * TT + t) * 64 + lane;
        out[o]    = 0.3f * m + 0.4f * cacc[r] + 0.3f * (pacc[r] + pbias) * ksum;
        memout[o] = m;
    }
}

extern "C" void kernel_launch(void* const* d_in, const int* in_sizes, int n_in,
                              void* d_out, int out_size, void* d_ws, size_t ws_size,
                              hipStream_t stream) {
    const float* x   = (const float*)d_in[0];
    const float* W   = (const float*)d_in[1];
    const float* PW  = (const float*)d_in[2];
    const float* pb  = (const float*)d_in[3];
    const float* kap = (const float*)d_in[4];
    const float* cf  = (const float*)d_in[5];

    float* out    = (float*)d_out;
    float* memout = out + (size_t)4 * TT * FF;

    __half2* wp = (__half2*)d_ws;

    hipLaunchKernelGGL(prep_kernel, dim3(1), dim3(64, 4), 0, stream, W, PW, wp);

    const int nblocks = 4 * (TT / TILE);   // 1024 = 4 per CU, fully resident
    hipLaunchKernelGGL(mcao_main, dim3(nblocks), dim3(512), 0, stream,
                       x, wp, pb, kap, cf, out, memout);
}

// Round 4
// 69.502 us; speedup vs baseline: 1.0193x; 1.0193x over previous
//
#include <hip/hip_runtime.h>
#include <hip/hip_fp16.h>
#include <math.h>

#define TT 8192
#define FF 64
#define TILE 32
#define HALO 50

__device__ __forceinline__ float rcpf(float x) { return __builtin_amdgcn_rcpf(x); }
__device__ __forceinline__ float rlane(float v, int j) {
    return __builtin_bit_cast(float,
        __builtin_amdgcn_readlane(__builtin_bit_cast(int, v), j));
}

// ---- prep: softmax rows of W; pack {softmax_w[i][j], proj_w[i][j]} as half2 at wp[j*64+i] ----
__global__ void prep_kernel(const float* __restrict__ W,
                            const float* __restrict__ PW,
                            __half2* __restrict__ wp) {
    const int lane = threadIdx.x;   // j
    const int wv   = threadIdx.y;   // 0..3
    for (int it = 0; it < 16; ++it) {
        const int r = wv * 16 + it; // i
        float v = W[r * 64 + lane];
        float m = v;
        #pragma unroll
        for (int off = 32; off >= 1; off >>= 1)
            m = fmaxf(m, __shfl_xor(m, off, 64));
        float e = __expf(v - m);
        float s = e;
        #pragma unroll
        for (int off = 32; off >= 1; off >>= 1)
            s += __shfl_xor(s, off, 64);
        const float w = e * rcpf(s);
        const float p = PW[r * 64 + lane];
        wp[lane * 64 + r] = __floats2half2_rn(w, p);   // wp[j][i]
    }
}

// ---- fused main kernel: 256 threads = 4 waves, 32 rows/block, 8 rows/wave ----
__global__ __launch_bounds__(256, 4)
void mcao_main(const float* __restrict__ x,
               const __half2* __restrict__ wp,
               const float* __restrict__ pb,
               const float* __restrict__ kap,
               const float* __restrict__ coeffs,
               float* __restrict__ out,
               float* __restrict__ memout) {
    __shared__ float   xs[(TILE + HALO) * 64];   // 20992 B
    __shared__ __half2 wp_lds[64 * 64];          // 16384 B  (total 37376 -> 4 blocks/CU)

    const int tid  = threadIdx.x;
    const int lane = tid & 63;
    const int wv   = tid >> 6;              // 0..3

    // XCD-aware bijective swizzle: 1024 blocks -> 128 consecutive tiles per XCD
    const int sw = (blockIdx.x & 7) * 128 + (blockIdx.x >> 3);
    const int b  = sw >> 8;                 // 0..3
    const int t0 = (sw & 255) * TILE;
    const float* xb = x + (size_t)b * TT * FF;

    // stage xs rows [t0-50, t0+32) (zero-pad t<0) and wp
    for (int i4 = tid; i4 < (TILE + HALO) * 16; i4 += 256) {
        const int e0 = i4 * 4;
        const int s  = e0 >> 6;
        const int f  = e0 & 63;
        const int t  = t0 - HALO + s;
        float4 v = make_float4(0.f, 0.f, 0.f, 0.f);
        if (t >= 0) v = *reinterpret_cast<const float4*>(xb + t * 64 + f);
        *reinterpret_cast<float4*>(&xs[e0]) = v;
    }
    #pragma unroll
    for (int k = 0; k < 4; ++k)
        reinterpret_cast<float4*>(wp_lds)[tid + 256 * k] =
            reinterpret_cast<const float4*>(wp)[tid + 256 * k];

    __syncthreads();

    const int base = 8 * wv;                // local first row of this wave

    // ---- FIR from LDS halo ----
    float macc[8] = {0.f, 0.f, 0.f, 0.f, 0.f, 0.f, 0.f, 0.f};
    #pragma unroll
    for (int s = 0; s < 58; ++s) {
        const float xv = xs[(base + s) * 64 + lane];
        #pragma unroll
        for (int r = 0; r < 8; ++r) {
            const int k = 50 + r - s;
            if (0 <= k && k <= 50)
                macc[r] = fmaf(coeffs[k], xv, macc[r]);
        }
    }

    // ---- per-row feature values, held in registers (lane = feature) ----
    float ti[8], ui[8], xr[8];
    #pragma unroll
    for (int r = 0; r < 8; ++r) {
        const float xi = xs[(base + r + HALO) * 64 + lane];
        const float E  = __expf(2.f * xi);
        ti[r] = fmaf(-2.f, rcpf(E + 1.f), 1.f);   // tanh(xi)
        ui[r] = __expf(-fabsf(xi));               // e^{-|xi|}
        xr[r] = xi;
    }

    // ---- coupling + proj: feature-j broadcast via v_readlane (no LDS pipe) ----
    float cacc[8] = {0.f, 0.f, 0.f, 0.f, 0.f, 0.f, 0.f, 0.f};
    float pacc[8] = {0.f, 0.f, 0.f, 0.f, 0.f, 0.f, 0.f, 0.f};
    #pragma unroll 8
    for (int j = 0; j < 64; ++j) {
        const __half2 wpj = wp_lds[j * 64 + lane];
        const float wj = __low2float(wpj);
        const float pj = __high2float(wpj);
        #pragma unroll
        for (int r = 0; r < 8; ++r) {
            const float tj = rlane(ti[r], j);
            const float uj = rlane(ui[r], j);
            const float xj = rlane(xr[r], j);
            const float d1 = fmaf(-ti[r], tj, 1.f);   // 1 - ti*tj
            const float d2 = fmaf(ui[r], uj, 1.f);    // 1 + ui*uj
            const float rr = rcpf(d1 * d2);
            cacc[r] = fmaf((ti[r] - tj) * wj, rr, cacc[r]);
            pacc[r] = fmaf(xj, pj, pacc[r]);
        }
    }

    const float kappa  = kap[0];
    const float inv1mr = rcpf(1.f - __expf(-kappa));
    const float pbias  = pb[lane];

    #pragma unroll
    for (int r = 0; r < 8; ++r) {
        const int   t    = t0 + base + r;
        const float ksum = (1.f - __expf(-kappa * (float)(t + 1))) * inv1mr;
        const float m    = macc[r];
        const size_t o   = (size_t)(b * TT + t) * 64 + lane;
        out[o]    = 0.3f * m + 0.4f * cacc[r] + 0.3f * (pacc[r] + pbias) * ksum;
        memout[o] = m;
    }
}

extern "C" void kernel_launch(void* const* d_in, const int* in_sizes, int n_in,
                              void* d_out, int out_size, void* d_ws, size_t ws_size,
                              hipStream_t stream) {
    const float* x   = (const float*)d_in[0];
    const float* W   = (const float*)d_in[1];
    const float* PW  = (const float*)d_in[2];
    const float* pb  = (const float*)d_in[3];
    const float* kap = (const float*)d_in[4];
    const float* cf  = (const float*)d_in[5];

    float* out    = (float*)d_out;
    float* memout = out + (size_t)4 * TT * FF;

    __half2* wp = (__half2*)d_ws;

    hipLaunchKernelGGL(prep_kernel, dim3(1), dim3(64, 4), 0, stream, W, PW, wp);

    const int nblocks = 4 * (TT / TILE);   // 1024 = 4 per CU, fully resident, no tail
    hipLaunchKernelGGL(mcao_main, dim3(nblocks), dim3(256), 0, stream,
                       x, wp, pb, kap, cf, out, memout);
}